// Round 2
// baseline (327.737 us; speedup 1.0000x reference)
//
#include <hip/hip_runtime.h>
#include <math.h>

#define N_NODES 20000
#define E_EDGES 320000
#define E_TOT   (E_EDGES + N_NODES)   // 340000 (edges + self loops)
#define NEG_SLOPE 0.2f

__device__ __forceinline__ float lrelu(float x) { return x > 0.f ? x : NEG_SLOPE * x; }

// ---------------- CSR build: histogram -> scan -> scatter ----------------
// NOTE: harness delivers ALL integer inputs as int32 (even int64 in the
// reference) — edge_index is const int*, 2*E elements.

__global__ void hist_k(const int* __restrict__ ei, int* __restrict__ counts) {
    int e = blockIdx.x * blockDim.x + threadIdx.x;
    if (e >= E_TOT) return;
    int d = (e < E_EDGES) ? ei[E_EDGES + e] : (e - E_EDGES);
    atomicAdd(&counts[d], 1);
}

__global__ void scan_k(const int* __restrict__ counts, int* __restrict__ offs,
                       int* __restrict__ cursor) {
    __shared__ int sums[256];
    int t = threadIdx.x;
    const int PER = (N_NODES + 255) / 256;   // 79
    int base = t * PER;
    int lsum = 0;
    for (int j = 0; j < PER; j++) {
        int idx = base + j;
        if (idx < N_NODES) lsum += counts[idx];
    }
    sums[t] = lsum;
    __syncthreads();
    for (int off = 1; off < 256; off <<= 1) {
        int v = (t >= off) ? sums[t - off] : 0;
        __syncthreads();
        sums[t] += v;
        __syncthreads();
    }
    int running = sums[t] - lsum;   // exclusive prefix
    for (int j = 0; j < PER; j++) {
        int idx = base + j;
        if (idx < N_NODES) {
            offs[idx] = running;
            cursor[idx] = running;
            running += counts[idx];
        }
    }
    if (t == 255) offs[N_NODES] = sums[255];
}

__global__ void scatter_k(const int* __restrict__ ei, int* __restrict__ cursor,
                          int* __restrict__ esorted) {
    int e = blockIdx.x * blockDim.x + threadIdx.x;
    if (e >= E_TOT) return;
    int s, d;
    if (e < E_EDGES) { s = ei[e]; d = ei[E_EDGES + e]; }
    else             { s = e - E_EDGES; d = s; }
    int pos = atomicAdd(&cursor[d], 1);
    esorted[pos] = s;
}

// ---------------- GEMM1: h = x @ W1  [20000x128]x[128x512] fp32 ----------------

__global__ __launch_bounds__(256) void gemm1_k(const float* __restrict__ A,
                                               const float* __restrict__ B,
                                               float* __restrict__ C) {
    __shared__ float As[32][68];  // [k][m], padded
    __shared__ float Bs[32][68];  // [k][n], padded
    int t = threadIdx.x;
    int tx = t & 15, ty = t >> 4;
    int m0 = blockIdx.x * 64, n0 = blockIdx.y * 64;
    float acc[4][4] = {};
    for (int k0 = 0; k0 < 128; k0 += 32) {
        {   // A tile: 64 rows x 32 k -> As[k][m]
            int kcol = t & 31, row = t >> 5;
            #pragma unroll
            for (int r = 0; r < 8; r++) {
                int m = row + r * 8;
                int gm = m0 + m;
                As[kcol][m] = (gm < N_NODES) ? A[gm * 128 + k0 + kcol] : 0.f;
            }
        }
        {   // B tile: 32 k x 64 n
            int col = t & 63, kr = t >> 6;
            #pragma unroll
            for (int r = 0; r < 8; r++) {
                int kk = kr + r * 4;
                Bs[kk][col] = B[(k0 + kk) * 512 + n0 + col];
            }
        }
        __syncthreads();
        #pragma unroll
        for (int kk = 0; kk < 32; kk++) {
            float4 a4 = *(const float4*)&As[kk][ty * 4];
            float4 b4 = *(const float4*)&Bs[kk][tx * 4];
            float a[4] = {a4.x, a4.y, a4.z, a4.w};
            float b[4] = {b4.x, b4.y, b4.z, b4.w};
            #pragma unroll
            for (int i = 0; i < 4; i++)
                #pragma unroll
                for (int j = 0; j < 4; j++)
                    acc[i][j] += a[i] * b[j];
        }
        __syncthreads();
    }
    #pragma unroll
    for (int i = 0; i < 4; i++) {
        int gm = m0 + ty * 4 + i;
        if (gm < N_NODES) {
            float4 v = make_float4(acc[i][0], acc[i][1], acc[i][2], acc[i][3]);
            *(float4*)&C[gm * 512 + n0 + tx * 4] = v;
        }
    }
}

// ---------------- attention scalars layer 1: a_src[n,h], a_dst[n,h] ----------------

__global__ void att1_k(const float* __restrict__ h, const float* __restrict__ att_s,
                       const float* __restrict__ att_d, float* __restrict__ as_,
                       float* __restrict__ ad_) {
    int gid = blockIdx.x * blockDim.x + threadIdx.x;
    int wid = gid >> 6;           // node
    int lane = threadIdx.x & 63;
    if (wid >= N_NODES) return;
    const float* row = h + (size_t)wid * 512 + lane * 8;
    float4 h0 = *(const float4*)row;
    float4 h1 = *(const float4*)(row + 4);
    float4 s0 = *(const float4*)(att_s + lane * 8);
    float4 s1 = *(const float4*)(att_s + lane * 8 + 4);
    float4 d0 = *(const float4*)(att_d + lane * 8);
    float4 d1 = *(const float4*)(att_d + lane * 8 + 4);
    float ps = h0.x*s0.x + h0.y*s0.y + h0.z*s0.z + h0.w*s0.w
             + h1.x*s1.x + h1.y*s1.y + h1.z*s1.z + h1.w*s1.w;
    float pd = h0.x*d0.x + h0.y*d0.y + h0.z*d0.z + h0.w*d0.w
             + h1.x*d1.x + h1.y*d1.y + h1.z*d1.z + h1.w*d1.w;
    // reduce within the 8 lanes of each head (lanes 8h..8h+7)
    ps += __shfl_xor(ps, 1); ps += __shfl_xor(ps, 2); ps += __shfl_xor(ps, 4);
    pd += __shfl_xor(pd, 1); pd += __shfl_xor(pd, 2); pd += __shfl_xor(pd, 4);
    if ((lane & 7) == 0) {
        int hd = lane >> 3;
        as_[wid * 8 + hd] = ps;
        ad_[wid * 8 + hd] = pd;
    }
}

// ---- layer-1 softmax + aggregation + ELU + fused layer-2 prep, block/node ----
// g row never hits global memory: after computing the 512-wide output row in
// registers we immediately reduce h2 = g_row @ W2 (512x2) and the layer-2
// attention scalars for this node.

__global__ __launch_bounds__(256) void agg1_k(const float* __restrict__ h,
                                              const float* __restrict__ as_,
                                              const float* __restrict__ ad_,
                                              const int* __restrict__ offs,
                                              const int* __restrict__ esorted,
                                              const float* __restrict__ b1,
                                              const float* __restrict__ W2,
                                              const float* __restrict__ as2,
                                              const float* __restrict__ ad2,
                                              float* __restrict__ h2,
                                              float* __restrict__ a2s,
                                              float* __restrict__ a2d) {
    __shared__ float red[256];
    __shared__ float mh[8], dh[8], adl[8];
    __shared__ float coef[64 * 8];
    __shared__ int srcs[64];
    __shared__ float wsum[8];   // 4 waves x 2 channels
    int i = blockIdx.x;
    int t = threadIdx.x;
    int hd = t & 7, grp = t >> 3;
    int off = offs[i], deg = offs[i + 1] - off;
    if (t < 8) adl[t] = ad_[i * 8 + t];
    __syncthreads();
    // pass 1: per-head max over incoming edges
    float lmax = -3.4e38f;
    for (int e = grp; e < deg; e += 32) {
        int s = esorted[off + e];
        lmax = fmaxf(lmax, lrelu(as_[s * 8 + hd] + adl[hd]));
    }
    red[hd * 32 + grp] = lmax;
    __syncthreads();
    for (int st = 16; st >= 1; st >>= 1) {
        if (grp < st) red[hd * 32 + grp] = fmaxf(red[hd * 32 + grp], red[hd * 32 + grp + st]);
        __syncthreads();
    }
    if (t < 8) mh[t] = red[t * 32];
    __syncthreads();
    // pass 2: per-head denom
    float lsum = 0.f;
    for (int e = grp; e < deg; e += 32) {
        int s = esorted[off + e];
        lsum += expf(lrelu(as_[s * 8 + hd] + adl[hd]) - mh[hd]);
    }
    red[hd * 32 + grp] = lsum;
    __syncthreads();
    for (int st = 16; st >= 1; st >>= 1) {
        if (grp < st) red[hd * 32 + grp] += red[hd * 32 + grp + st];
        __syncthreads();
    }
    if (t < 8) dh[t] = 1.f / red[t * 32];
    __syncthreads();
    // pass 3: chunked weighted aggregation; thread t owns output elems t, t+256
    float acc0 = 0.f, acc1 = 0.f;
    int h0 = t >> 6;   // head of elem t (elem t+256 has head h0+4)
    for (int base = 0; base < deg; base += 64) {
        int cnt = min(64, deg - base);
        if (t < cnt) srcs[t] = esorted[off + base + t];
        __syncthreads();
        for (int idx = t; idx < cnt * 8; idx += 256) {
            int e = idx >> 3, hh = idx & 7;
            int s = srcs[e];
            coef[idx] = expf(lrelu(as_[s * 8 + hh] + adl[hh]) - mh[hh]) * dh[hh];
        }
        __syncthreads();
        for (int e = 0; e < cnt; e++) {
            int s = srcs[e];
            const float* rw = h + (size_t)s * 512;
            acc0 += coef[e * 8 + h0]     * rw[t];
            acc1 += coef[e * 8 + h0 + 4] * rw[t + 256];
        }
        __syncthreads();
    }
    // bias + ELU -> g row elems (t, t+256) in registers
    float v0 = acc0 + b1[t];
    float v1 = acc1 + b1[t + 256];
    v0 = v0 > 0.f ? v0 : expm1f(v0);
    v1 = v1 > 0.f ? v1 : expm1f(v1);
    // fused layer-2 prep: h2[i,c] = sum_j g[j] * W2[j,c]
    float p0 = v0 * W2[t * 2]     + v1 * W2[(t + 256) * 2];
    float p1 = v0 * W2[t * 2 + 1] + v1 * W2[(t + 256) * 2 + 1];
    #pragma unroll
    for (int m = 1; m < 64; m <<= 1) { p0 += __shfl_xor(p0, m); p1 += __shfl_xor(p1, m); }
    int lane = t & 63, wv = t >> 6;
    if (lane == 0) { wsum[wv] = p0; wsum[wv + 4] = p1; }
    __syncthreads();
    if (t == 0) {
        float c0 = wsum[0] + wsum[1] + wsum[2] + wsum[3];
        float c1 = wsum[4] + wsum[5] + wsum[6] + wsum[7];
        h2[i * 2] = c0; h2[i * 2 + 1] = c1;
        a2s[i] = c0 * as2[0] + c1 * as2[1];
        a2d[i] = c0 * ad2[0] + c1 * ad2[1];
    }
}

// ---------------- layer-2 softmax + aggregation, wave per dst node ----------------

__global__ void agg2_k(const float* __restrict__ h2, const float* __restrict__ a2s,
                       const float* __restrict__ a2d, const int* __restrict__ offs,
                       const int* __restrict__ esorted, const float* __restrict__ b2,
                       float* __restrict__ out) {
    int gid = blockIdx.x * blockDim.x + threadIdx.x;
    int wid = gid >> 6;
    int lane = threadIdx.x & 63;
    if (wid >= N_NODES) return;
    int off = offs[wid], deg = offs[wid + 1] - off;
    float adi = a2d[wid];
    float lmax = -3.4e38f;
    for (int e = lane; e < deg; e += 64) {
        int s = esorted[off + e];
        lmax = fmaxf(lmax, lrelu(a2s[s] + adi));
    }
    #pragma unroll
    for (int m = 1; m < 64; m <<= 1) lmax = fmaxf(lmax, __shfl_xor(lmax, m));
    float lsum = 0.f, o0 = 0.f, o1 = 0.f;
    for (int e = lane; e < deg; e += 64) {
        int s = esorted[off + e];
        float ex = expf(lrelu(a2s[s] + adi) - lmax);
        lsum += ex;
        o0 += ex * h2[s * 2];
        o1 += ex * h2[s * 2 + 1];
    }
    #pragma unroll
    for (int m = 1; m < 64; m <<= 1) {
        lsum += __shfl_xor(lsum, m);
        o0 += __shfl_xor(o0, m);
        o1 += __shfl_xor(o1, m);
    }
    if (lane == 0) {
        float inv = 1.f / lsum;
        out[wid * 2]     = o0 * inv + b2[0];
        out[wid * 2 + 1] = o1 * inv + b2[1];
    }
}

// ---------------- launch ----------------

extern "C" void kernel_launch(void* const* d_in, const int* in_sizes, int n_in,
                              void* d_out, int out_size, void* d_ws, size_t ws_size,
                              hipStream_t stream) {
    const float* x        = (const float*)d_in[0];
    const int*   ei       = (const int*)d_in[1];    // int32 per harness contract
    const float* W1       = (const float*)d_in[2];
    const float* att_src1 = (const float*)d_in[3];
    const float* att_dst1 = (const float*)d_in[4];
    const float* b1       = (const float*)d_in[5];
    const float* W2       = (const float*)d_in[6];
    const float* att_src2 = (const float*)d_in[7];
    const float* att_dst2 = (const float*)d_in[8];
    const float* b2       = (const float*)d_in[9];
    float* out = (float*)d_out;

    // workspace layout (~44.2 MB)
    float* h1  = (float*)d_ws;                       // 20000*512
    float* as1 = h1 + (size_t)N_NODES * 512;         // 20000*8
    float* ad1 = as1 + N_NODES * 8;                  // 20000*8
    float* h2  = ad1 + N_NODES * 8;                  // 20000*2
    float* a2s = h2 + N_NODES * 2;                   // 20000
    float* a2d = a2s + N_NODES;                      // 20000
    int* counts  = (int*)(a2d + N_NODES);            // 20000
    int* offs    = counts + N_NODES;                 // 20001 (+pad)
    int* cursor  = offs + N_NODES + 8;               // 20000
    int* esorted = cursor + N_NODES;                 // 340000

    hipMemsetAsync(counts, 0, N_NODES * sizeof(int), stream);

    int eb = (E_TOT + 255) / 256;
    hist_k<<<eb, 256, 0, stream>>>(ei, counts);
    scan_k<<<1, 256, 0, stream>>>(counts, offs, cursor);
    scatter_k<<<eb, 256, 0, stream>>>(ei, cursor, esorted);

    dim3 ggrid((N_NODES + 63) / 64, 8);
    gemm1_k<<<ggrid, 256, 0, stream>>>(x, W1, h1);

    int nwb = (N_NODES * 64 + 255) / 256;   // wave-per-node kernels
    att1_k<<<nwb, 256, 0, stream>>>(h1, att_src1, att_dst1, as1, ad1);
    agg1_k<<<N_NODES, 256, 0, stream>>>(h1, as1, ad1, offs, esorted, b1,
                                        W2, att_src2, att_dst2, h2, a2s, a2d);
    agg2_k<<<nwb, 256, 0, stream>>>(h2, a2s, a2d, offs, esorted, b2, out);
}

// Round 3
// 284.394 us; speedup vs baseline: 1.1524x; 1.1524x over previous
//
#include <hip/hip_runtime.h>
#include <math.h>

#define N_NODES 20000
#define E_EDGES 320000
#define E_TOT   (E_EDGES + N_NODES)   // 340000 (edges + self loops)
#define NEG_SLOPE 0.2f

__device__ __forceinline__ float lrelu(float x) { return x > 0.f ? x : NEG_SLOPE * x; }

// ---------------- CSR build: histogram -> scan -> scatter ----------------
// Harness delivers ALL integer inputs as int32 — edge_index is const int*.

__global__ void hist_k(const int* __restrict__ ei, int* __restrict__ counts) {
    int e = blockIdx.x * blockDim.x + threadIdx.x;
    if (e >= E_TOT) return;
    int d = (e < E_EDGES) ? ei[E_EDGES + e] : (e - E_EDGES);
    atomicAdd(&counts[d], 1);
}

__global__ void scan_k(const int* __restrict__ counts, int* __restrict__ offs,
                       int* __restrict__ cursor) {
    __shared__ int sums[256];
    int t = threadIdx.x;
    const int PER = (N_NODES + 255) / 256;   // 79
    int base = t * PER;
    int lsum = 0;
    for (int j = 0; j < PER; j++) {
        int idx = base + j;
        if (idx < N_NODES) lsum += counts[idx];
    }
    sums[t] = lsum;
    __syncthreads();
    for (int off = 1; off < 256; off <<= 1) {
        int v = (t >= off) ? sums[t - off] : 0;
        __syncthreads();
        sums[t] += v;
        __syncthreads();
    }
    int running = sums[t] - lsum;   // exclusive prefix
    for (int j = 0; j < PER; j++) {
        int idx = base + j;
        if (idx < N_NODES) {
            offs[idx] = running;
            cursor[idx] = running;
            running += counts[idx];
        }
    }
    if (t == 255) offs[N_NODES] = sums[255];
}

__global__ void scatter_k(const int* __restrict__ ei, int* __restrict__ cursor,
                          int* __restrict__ esorted) {
    int e = blockIdx.x * blockDim.x + threadIdx.x;
    if (e >= E_TOT) return;
    int s, d;
    if (e < E_EDGES) { s = ei[e]; d = ei[E_EDGES + e]; }
    else             { s = e - E_EDGES; d = s; }
    int pos = atomicAdd(&cursor[d], 1);
    esorted[pos] = s;
}

// ---- GEMM1 + fused att1: h = x@W1 (bf16 out), a_src/a_dst from fp32 accs ----
// Each block computes a 64x64 tile = 64 nodes x one full head (HID=64,
// blockIdx.y == head). Attention scalars reduce over the head dim in-register.

__global__ __launch_bounds__(256) void gemm1_k(const float* __restrict__ A,
                                               const float* __restrict__ B,
                                               const float* __restrict__ att_s,
                                               const float* __restrict__ att_d,
                                               unsigned short* __restrict__ Hb,
                                               float* __restrict__ as_,
                                               float* __restrict__ ad_) {
    __shared__ float As[32][68];  // [k][m], padded
    __shared__ float Bs[32][68];  // [k][n], padded
    int t = threadIdx.x;
    int tx = t & 15, ty = t >> 4;
    int m0 = blockIdx.x * 64;
    int head = blockIdx.y;
    int n0 = head * 64;
    float acc[4][4] = {};
    for (int k0 = 0; k0 < 128; k0 += 32) {
        {   // A tile: 64 rows x 32 k -> As[k][m]
            int kcol = t & 31, row = t >> 5;
            #pragma unroll
            for (int r = 0; r < 8; r++) {
                int m = row + r * 8;
                int gm = m0 + m;
                As[kcol][m] = (gm < N_NODES) ? A[gm * 128 + k0 + kcol] : 0.f;
            }
        }
        {   // B tile: 32 k x 64 n
            int col = t & 63, kr = t >> 6;
            #pragma unroll
            for (int r = 0; r < 8; r++) {
                int kk = kr + r * 4;
                Bs[kk][col] = B[(k0 + kk) * 512 + n0 + col];
            }
        }
        __syncthreads();
        #pragma unroll
        for (int kk = 0; kk < 32; kk++) {
            float4 a4 = *(const float4*)&As[kk][ty * 4];
            float4 b4 = *(const float4*)&Bs[kk][tx * 4];
            float a[4] = {a4.x, a4.y, a4.z, a4.w};
            float b[4] = {b4.x, b4.y, b4.z, b4.w};
            #pragma unroll
            for (int i = 0; i < 4; i++)
                #pragma unroll
                for (int j = 0; j < 4; j++)
                    acc[i][j] += a[i] * b[j];
        }
        __syncthreads();
    }
    // attention vectors for this head, cols tx*4..tx*4+3
    float sa[4], da[4];
    #pragma unroll
    for (int j = 0; j < 4; j++) {
        sa[j] = att_s[head * 64 + tx * 4 + j];
        da[j] = att_d[head * 64 + tx * 4 + j];
    }
    #pragma unroll
    for (int i = 0; i < 4; i++) {
        int gm = m0 + ty * 4 + i;
        float ps = acc[i][0]*sa[0] + acc[i][1]*sa[1] + acc[i][2]*sa[2] + acc[i][3]*sa[3];
        float pd = acc[i][0]*da[0] + acc[i][1]*da[1] + acc[i][2]*da[2] + acc[i][3]*da[3];
        // reduce across tx (16 lanes, within wave)
        ps += __shfl_xor(ps, 1); ps += __shfl_xor(ps, 2);
        ps += __shfl_xor(ps, 4); ps += __shfl_xor(ps, 8);
        pd += __shfl_xor(pd, 1); pd += __shfl_xor(pd, 2);
        pd += __shfl_xor(pd, 4); pd += __shfl_xor(pd, 8);
        if (gm < N_NODES) {
            if (tx == 0) { as_[gm * 8 + head] = ps; ad_[gm * 8 + head] = pd; }
            // bf16 store: 4 cols = 2 uints
            unsigned int lo0 = (__builtin_bit_cast(unsigned int, acc[i][0]) + 0x8000u) >> 16;
            unsigned int hi0 = (__builtin_bit_cast(unsigned int, acc[i][1]) + 0x8000u) >> 16;
            unsigned int lo1 = (__builtin_bit_cast(unsigned int, acc[i][2]) + 0x8000u) >> 16;
            unsigned int hi1 = (__builtin_bit_cast(unsigned int, acc[i][3]) + 0x8000u) >> 16;
            unsigned int* dst = (unsigned int*)&Hb[(size_t)gm * 512 + n0 + tx * 4];
            dst[0] = lo0 | (hi0 << 16);
            dst[1] = lo1 | (hi1 << 16);
        }
    }
}

// ---- layer-1 single-pass softmax-aggregation + ELU + fused layer-2 prep ----
// No max subtraction (logits ~N(0,2), exp safe in fp32; softmax shift-invariant).
// Per 64-edge chunk: gather unnormalized weights into LDS + accumulate per-head
// denominator, then gather bf16 h rows weighted into registers. Normalize once.

__global__ __launch_bounds__(256) void agg1_k(const unsigned int* __restrict__ hu,
                                              const float* __restrict__ as_,
                                              const float* __restrict__ ad_,
                                              const int* __restrict__ offs,
                                              const int* __restrict__ esorted,
                                              const float* __restrict__ b1,
                                              const float* __restrict__ W2,
                                              const float* __restrict__ as2,
                                              const float* __restrict__ ad2,
                                              float* __restrict__ h2,
                                              float* __restrict__ a2s,
                                              float* __restrict__ a2d) {
    __shared__ float red[256];
    __shared__ float coef[64 * 8];
    __shared__ int srcs[64];
    __shared__ float adl[8], denom[8], wsum[8];
    int i = blockIdx.x;
    int t = threadIdx.x;
    int hd = t & 7, grp = t >> 3;      // coef-fill / denom mapping
    int hd2 = t >> 5;                  // head of feature elems 2t, 2t+1
    int off = offs[i], deg = offs[i + 1] - off;
    if (t < 8) { adl[t] = ad_[i * 8 + t]; denom[t] = 0.f; }
    __syncthreads();
    float acc0 = 0.f, acc1 = 0.f;      // g elems 2t, 2t+1 (unnormalized)
    for (int base = 0; base < deg; base += 64) {
        int cnt = min(64, deg - base);
        if (t < cnt) srcs[t] = esorted[off + base + t];
        __syncthreads();
        // fill unnormalized weights; thread t covers idx = t and t+256 (same head hd)
        int ncf = cnt * 8;
        float w0 = 0.f, w1 = 0.f;
        if (t < ncf) {
            int s = srcs[t >> 3];
            w0 = expf(lrelu(as_[s * 8 + hd] + adl[hd]));
            coef[t] = w0;
        }
        if (t + 256 < ncf) {
            int s = srcs[(t >> 3) + 32];
            w1 = expf(lrelu(as_[s * 8 + hd] + adl[hd]));
            coef[t + 256] = w1;
        }
        red[t] = w0 + w1;               // red[grp*8+hd], stride-1 = conflict-free
        __syncthreads();
        #pragma unroll
        for (int st = 16; st >= 1; st >>= 1) {
            if (grp < st) red[t] += red[t + st * 8];
            __syncthreads();
        }
        if (t < 8) denom[t] += red[t];
        __syncthreads();
        // weighted aggregation of bf16 rows; thread t loads elems {2t,2t+1} as one uint
        for (int e = 0; e < cnt; e++) {
            int s = srcs[e];
            unsigned int v = hu[s * 256 + t];
            float c = coef[e * 8 + hd2];
            float f0 = __builtin_bit_cast(float, v << 16);
            float f1 = __builtin_bit_cast(float, v & 0xffff0000u);
            acc0 += c * f0;
            acc1 += c * f1;
        }
        __syncthreads();
    }
    // normalize, bias, ELU
    float inv = 1.f / denom[hd2];
    float v0 = acc0 * inv + b1[2 * t];
    float v1 = acc1 * inv + b1[2 * t + 1];
    v0 = v0 > 0.f ? v0 : expm1f(v0);
    v1 = v1 > 0.f ? v1 : expm1f(v1);
    // fused layer-2 prep: h2[i,c] = sum_j g[j] * W2[j,c]
    float p0 = v0 * W2[4 * t]     + v1 * W2[4 * t + 2];
    float p1 = v0 * W2[4 * t + 1] + v1 * W2[4 * t + 3];
    #pragma unroll
    for (int m = 1; m < 64; m <<= 1) { p0 += __shfl_xor(p0, m); p1 += __shfl_xor(p1, m); }
    int lane = t & 63, wv = t >> 6;
    if (lane == 0) { wsum[wv] = p0; wsum[wv + 4] = p1; }
    __syncthreads();
    if (t == 0) {
        float c0 = wsum[0] + wsum[1] + wsum[2] + wsum[3];
        float c1 = wsum[4] + wsum[5] + wsum[6] + wsum[7];
        h2[i * 2] = c0; h2[i * 2 + 1] = c1;
        a2s[i] = c0 * as2[0] + c1 * as2[1];
        a2d[i] = c0 * ad2[0] + c1 * ad2[1];
    }
}

// ---- layer-2 single-pass softmax + aggregation, wave per dst node ----

__global__ void agg2_k(const float* __restrict__ h2, const float* __restrict__ a2s,
                       const float* __restrict__ a2d, const int* __restrict__ offs,
                       const int* __restrict__ esorted, const float* __restrict__ b2,
                       float* __restrict__ out) {
    int gid = blockIdx.x * blockDim.x + threadIdx.x;
    int wid = gid >> 6;
    int lane = threadIdx.x & 63;
    if (wid >= N_NODES) return;
    int off = offs[wid], deg = offs[wid + 1] - off;
    float adi = a2d[wid];
    float lsum = 0.f, o0 = 0.f, o1 = 0.f;
    for (int e = lane; e < deg; e += 64) {
        int s = esorted[off + e];
        float ex = expf(lrelu(a2s[s] + adi));
        lsum += ex;
        o0 += ex * h2[s * 2];
        o1 += ex * h2[s * 2 + 1];
    }
    #pragma unroll
    for (int m = 1; m < 64; m <<= 1) {
        lsum += __shfl_xor(lsum, m);
        o0 += __shfl_xor(o0, m);
        o1 += __shfl_xor(o1, m);
    }
    if (lane == 0) {
        float inv = 1.f / lsum;
        out[wid * 2]     = o0 * inv + b2[0];
        out[wid * 2 + 1] = o1 * inv + b2[1];
    }
}

// ---------------- launch ----------------

extern "C" void kernel_launch(void* const* d_in, const int* in_sizes, int n_in,
                              void* d_out, int out_size, void* d_ws, size_t ws_size,
                              hipStream_t stream) {
    const float* x        = (const float*)d_in[0];
    const int*   ei       = (const int*)d_in[1];    // int32 per harness contract
    const float* W1       = (const float*)d_in[2];
    const float* att_src1 = (const float*)d_in[3];
    const float* att_dst1 = (const float*)d_in[4];
    const float* b1       = (const float*)d_in[5];
    const float* W2       = (const float*)d_in[6];
    const float* att_src2 = (const float*)d_in[7];
    const float* att_dst2 = (const float*)d_in[8];
    const float* b2       = (const float*)d_in[9];
    float* out = (float*)d_out;

    // workspace layout (~24 MB)
    unsigned short* h1b = (unsigned short*)d_ws;     // 20000*512 bf16
    float* as1 = (float*)(h1b + (size_t)N_NODES * 512);  // 20000*8
    float* ad1 = as1 + N_NODES * 8;                  // 20000*8
    float* h2  = ad1 + N_NODES * 8;                  // 20000*2
    float* a2s = h2 + N_NODES * 2;                   // 20000
    float* a2d = a2s + N_NODES;                      // 20000
    int* counts  = (int*)(a2d + N_NODES);            // 20000
    int* offs    = counts + N_NODES;                 // 20001 (+pad)
    int* cursor  = offs + N_NODES + 8;               // 20000
    int* esorted = cursor + N_NODES;                 // 340000

    hipMemsetAsync(counts, 0, N_NODES * sizeof(int), stream);

    int eb = (E_TOT + 255) / 256;
    hist_k<<<eb, 256, 0, stream>>>(ei, counts);
    scan_k<<<1, 256, 0, stream>>>(counts, offs, cursor);
    scatter_k<<<eb, 256, 0, stream>>>(ei, cursor, esorted);

    dim3 ggrid((N_NODES + 63) / 64, 8);
    gemm1_k<<<ggrid, 256, 0, stream>>>(x, W1, att_src1, att_dst1, h1b, as1, ad1);

    agg1_k<<<N_NODES, 256, 0, stream>>>((const unsigned int*)h1b, as1, ad1, offs,
                                        esorted, b1, W2, att_src2, att_dst2,
                                        h2, a2s, a2d);
    int nwb = (N_NODES * 64 + 255) / 256;
    agg2_k<<<nwb, 256, 0, stream>>>(h2, a2s, a2d, offs, esorted, b2, out);
}

// Round 4
// 226.069 us; speedup vs baseline: 1.4497x; 1.2580x over previous
//
#include <hip/hip_runtime.h>
#include <math.h>

#define N_NODES 20000
#define E_EDGES 320000
#define E_TOT   (E_EDGES + N_NODES)   // 340000 (edges + self loops)
#define NEG_SLOPE 0.2f
#define NBLK 79                       // ceil(N_NODES/256)

__device__ __forceinline__ float lrelu(float x) { return x > 0.f ? x : NEG_SLOPE * x; }
__device__ __forceinline__ float bflo(unsigned int v) { return __builtin_bit_cast(float, v << 16); }
__device__ __forceinline__ float bfhi(unsigned int v) { return __builtin_bit_cast(float, v & 0xffff0000u); }

// ---------------- CSR build: histogram -> hierarchical scan -> scatter --------
// Harness delivers ALL integer inputs as int32 — edge_index is const int*.

__global__ void hist_k(const int* __restrict__ ei, int* __restrict__ counts) {
    int e = blockIdx.x * blockDim.x + threadIdx.x;
    if (e >= E_TOT) return;
    int d = (e < E_EDGES) ? ei[E_EDGES + e] : (e - E_EDGES);
    atomicAdd(&counts[d], 1);
}

__global__ void scanA_k(const int* __restrict__ counts, int* __restrict__ local,
                        int* __restrict__ partials) {
    __shared__ int sdata[256];
    int b = blockIdx.x, t = threadIdx.x;
    int idx = b * 256 + t;
    int v = (idx < N_NODES) ? counts[idx] : 0;
    sdata[t] = v;
    __syncthreads();
    for (int o = 1; o < 256; o <<= 1) {
        int u = (t >= o) ? sdata[t - o] : 0;
        __syncthreads();
        sdata[t] += u;
        __syncthreads();
    }
    if (idx < N_NODES) local[idx] = sdata[t] - v;   // exclusive within block
    if (t == 255) partials[b] = sdata[255];
}

__global__ void scanB_k(const int* __restrict__ partials, int* __restrict__ pbase) {
    __shared__ int s[128];
    int t = threadIdx.x;
    int v = (t < NBLK) ? partials[t] : 0;
    s[t] = v;
    __syncthreads();
    for (int o = 1; o < 128; o <<= 1) {
        int u = (t >= o) ? s[t - o] : 0;
        __syncthreads();
        s[t] += u;
        __syncthreads();
    }
    if (t < NBLK) pbase[t] = s[t] - v;              // exclusive
}

__global__ void scanC_k(const int* __restrict__ local, const int* __restrict__ pbase,
                        int* __restrict__ offs, int* __restrict__ cursor) {
    int idx = blockIdx.x * 256 + threadIdx.x;
    if (idx < N_NODES) {
        int o = local[idx] + pbase[blockIdx.x];
        offs[idx] = o;
        cursor[idx] = o;
    }
    if (idx == 0) offs[N_NODES] = E_TOT;
}

__global__ void scatter_k(const int* __restrict__ ei, int* __restrict__ cursor,
                          int* __restrict__ esorted) {
    int e = blockIdx.x * blockDim.x + threadIdx.x;
    if (e >= E_TOT) return;
    int s, d;
    if (e < E_EDGES) { s = ei[e]; d = ei[E_EDGES + e]; }
    else             { s = e - E_EDGES; d = s; }
    int pos = atomicAdd(&cursor[d], 1);
    esorted[pos] = s;
}

// ---- GEMM1 + fused att1: h = x@W1 (bf16 out), a_src/a_dst from fp32 accs ----

__global__ __launch_bounds__(256) void gemm1_k(const float* __restrict__ A,
                                               const float* __restrict__ B,
                                               const float* __restrict__ att_s,
                                               const float* __restrict__ att_d,
                                               unsigned short* __restrict__ Hb,
                                               float* __restrict__ as_,
                                               float* __restrict__ ad_) {
    __shared__ float As[32][68];  // [k][m], padded
    __shared__ float Bs[32][68];  // [k][n], padded
    int t = threadIdx.x;
    int tx = t & 15, ty = t >> 4;
    int m0 = blockIdx.x * 64;
    int head = blockIdx.y;
    int n0 = head * 64;
    float acc[4][4] = {};
    for (int k0 = 0; k0 < 128; k0 += 32) {
        {   // A tile: 64 rows x 32 k -> As[k][m]
            int kcol = t & 31, row = t >> 5;
            #pragma unroll
            for (int r = 0; r < 8; r++) {
                int m = row + r * 8;
                int gm = m0 + m;
                As[kcol][m] = (gm < N_NODES) ? A[gm * 128 + k0 + kcol] : 0.f;
            }
        }
        {   // B tile: 32 k x 64 n
            int col = t & 63, kr = t >> 6;
            #pragma unroll
            for (int r = 0; r < 8; r++) {
                int kk = kr + r * 4;
                Bs[kk][col] = B[(k0 + kk) * 512 + n0 + col];
            }
        }
        __syncthreads();
        #pragma unroll
        for (int kk = 0; kk < 32; kk++) {
            float4 a4 = *(const float4*)&As[kk][ty * 4];
            float4 b4 = *(const float4*)&Bs[kk][tx * 4];
            float a[4] = {a4.x, a4.y, a4.z, a4.w};
            float b[4] = {b4.x, b4.y, b4.z, b4.w};
            #pragma unroll
            for (int i = 0; i < 4; i++)
                #pragma unroll
                for (int j = 0; j < 4; j++)
                    acc[i][j] += a[i] * b[j];
        }
        __syncthreads();
    }
    float sa[4], da[4];
    #pragma unroll
    for (int j = 0; j < 4; j++) {
        sa[j] = att_s[head * 64 + tx * 4 + j];
        da[j] = att_d[head * 64 + tx * 4 + j];
    }
    #pragma unroll
    for (int i = 0; i < 4; i++) {
        int gm = m0 + ty * 4 + i;
        float ps = acc[i][0]*sa[0] + acc[i][1]*sa[1] + acc[i][2]*sa[2] + acc[i][3]*sa[3];
        float pd = acc[i][0]*da[0] + acc[i][1]*da[1] + acc[i][2]*da[2] + acc[i][3]*da[3];
        ps += __shfl_xor(ps, 1); ps += __shfl_xor(ps, 2);
        ps += __shfl_xor(ps, 4); ps += __shfl_xor(ps, 8);
        pd += __shfl_xor(pd, 1); pd += __shfl_xor(pd, 2);
        pd += __shfl_xor(pd, 4); pd += __shfl_xor(pd, 8);
        if (gm < N_NODES) {
            if (tx == 0) { as_[gm * 8 + head] = ps; ad_[gm * 8 + head] = pd; }
            unsigned int lo0 = (__builtin_bit_cast(unsigned int, acc[i][0]) + 0x8000u) >> 16;
            unsigned int hi0 = (__builtin_bit_cast(unsigned int, acc[i][1]) + 0x8000u) >> 16;
            unsigned int lo1 = (__builtin_bit_cast(unsigned int, acc[i][2]) + 0x8000u) >> 16;
            unsigned int hi1 = (__builtin_bit_cast(unsigned int, acc[i][3]) + 0x8000u) >> 16;
            unsigned int* dst = (unsigned int*)&Hb[(size_t)gm * 512 + n0 + tx * 4];
            dst[0] = lo0 | (hi0 << 16);
            dst[1] = lo1 | (hi1 << 16);
        }
    }
}

// ---- layer-1 softmax-aggregation, wave-per-edge-slice, no main-loop syncs ----
// Wave wv handles edges e ≡ wv (mod 4). Each lane owns 8 contiguous feature
// elems (one uint4 of bf16), all in one head (hd = lane>>3). Coefs computed
// redundantly per lane; denominator accumulated inline (free — value already
// in-register). One cross-wave LDS combine at the end. Epilogue fuses bias,
// ELU, and the 512x2 layer-2 projection; packs (h2c0,h2c1,a2s) into float4.

__global__ __launch_bounds__(256) void agg1_k(const uint4* __restrict__ hu4,
                                              const float* __restrict__ as_,
                                              const float* __restrict__ ad_,
                                              const int* __restrict__ offs,
                                              const int* __restrict__ esorted,
                                              const float* __restrict__ b1,
                                              const float* __restrict__ W2,
                                              const float* __restrict__ as2,
                                              const float* __restrict__ ad2,
                                              float4* __restrict__ p2,
                                              float* __restrict__ a2d) {
    __shared__ float part[4][512];
    __shared__ float dpart[4][8];
    int i = blockIdx.x;
    int t = threadIdx.x;
    int lane = t & 63, wv = t >> 6;
    int hd = lane >> 3;
    int off = offs[i], deg = offs[i + 1] - off;
    float adh = ad_[i * 8 + hd];
    float acc[8] = {0.f, 0.f, 0.f, 0.f, 0.f, 0.f, 0.f, 0.f};
    float dsum = 0.f;
    int e = wv;
    for (; e + 4 < deg; e += 8) {       // 2 edges in flight
        int s0 = esorted[off + e];
        int s1 = esorted[off + e + 4];
        float a0 = as_[s0 * 8 + hd];
        float a1 = as_[s1 * 8 + hd];
        uint4 v0 = hu4[s0 * 64 + lane];
        uint4 v1 = hu4[s1 * 64 + lane];
        float c0 = __expf(lrelu(a0 + adh));
        float c1 = __expf(lrelu(a1 + adh));
        dsum += c0 + c1;
        acc[0] += c0 * bflo(v0.x); acc[1] += c0 * bfhi(v0.x);
        acc[2] += c0 * bflo(v0.y); acc[3] += c0 * bfhi(v0.y);
        acc[4] += c0 * bflo(v0.z); acc[5] += c0 * bfhi(v0.z);
        acc[6] += c0 * bflo(v0.w); acc[7] += c0 * bfhi(v0.w);
        acc[0] += c1 * bflo(v1.x); acc[1] += c1 * bfhi(v1.x);
        acc[2] += c1 * bflo(v1.y); acc[3] += c1 * bfhi(v1.y);
        acc[4] += c1 * bflo(v1.z); acc[5] += c1 * bfhi(v1.z);
        acc[6] += c1 * bflo(v1.w); acc[7] += c1 * bfhi(v1.w);
    }
    if (e < deg) {
        int s0 = esorted[off + e];
        float a0 = as_[s0 * 8 + hd];
        uint4 v0 = hu4[s0 * 64 + lane];
        float c0 = __expf(lrelu(a0 + adh));
        dsum += c0;
        acc[0] += c0 * bflo(v0.x); acc[1] += c0 * bfhi(v0.x);
        acc[2] += c0 * bflo(v0.y); acc[3] += c0 * bfhi(v0.y);
        acc[4] += c0 * bflo(v0.z); acc[5] += c0 * bfhi(v0.z);
        acc[6] += c0 * bflo(v0.w); acc[7] += c0 * bfhi(v0.w);
    }
    *(float4*)&part[wv][lane * 8]     = make_float4(acc[0], acc[1], acc[2], acc[3]);
    *(float4*)&part[wv][lane * 8 + 4] = make_float4(acc[4], acc[5], acc[6], acc[7]);
    if ((lane & 7) == 0) dpart[wv][hd] = dsum;
    __syncthreads();
    if (wv == 0) {
        float den = dpart[0][hd] + dpart[1][hd] + dpart[2][hd] + dpart[3][hd];
        float inv = 1.f / den;
        float p0 = 0.f, p1 = 0.f;
        #pragma unroll
        for (int j = 0; j < 8; j++) {
            int col = lane * 8 + j;
            float v = (part[0][col] + part[1][col] + part[2][col] + part[3][col]) * inv
                    + b1[col];
            v = v > 0.f ? v : expm1f(v);
            p0 += v * W2[col * 2];
            p1 += v * W2[col * 2 + 1];
        }
        #pragma unroll
        for (int m = 1; m < 64; m <<= 1) { p0 += __shfl_xor(p0, m); p1 += __shfl_xor(p1, m); }
        if (lane == 0) {
            float a2sv = p0 * as2[0] + p1 * as2[1];
            p2[i] = make_float4(p0, p1, a2sv, 0.f);
            a2d[i] = p0 * ad2[0] + p1 * ad2[1];
        }
    }
}

// ---- layer-2 single-pass softmax + aggregation, wave per dst node ----
// p2[s] = (h2c0, h2c1, a2s, -) : one dwordx4 gather per edge.

__global__ void agg2_k(const float4* __restrict__ p2, const float* __restrict__ a2d,
                       const int* __restrict__ offs, const int* __restrict__ esorted,
                       const float* __restrict__ b2, float* __restrict__ out) {
    int gid = blockIdx.x * blockDim.x + threadIdx.x;
    int wid = gid >> 6;
    int lane = threadIdx.x & 63;
    if (wid >= N_NODES) return;
    int off = offs[wid], deg = offs[wid + 1] - off;
    float adi = a2d[wid];
    float lsum = 0.f, o0 = 0.f, o1 = 0.f;
    for (int e = lane; e < deg; e += 64) {
        int s = esorted[off + e];
        float4 q = p2[s];
        float ex = __expf(lrelu(q.z + adi));
        lsum += ex;
        o0 += ex * q.x;
        o1 += ex * q.y;
    }
    #pragma unroll
    for (int m = 1; m < 64; m <<= 1) {
        lsum += __shfl_xor(lsum, m);
        o0 += __shfl_xor(o0, m);
        o1 += __shfl_xor(o1, m);
    }
    if (lane == 0) {
        float inv = 1.f / lsum;
        out[wid * 2]     = o0 * inv + b2[0];
        out[wid * 2 + 1] = o1 * inv + b2[1];
    }
}

// ---------------- launch ----------------

extern "C" void kernel_launch(void* const* d_in, const int* in_sizes, int n_in,
                              void* d_out, int out_size, void* d_ws, size_t ws_size,
                              hipStream_t stream) {
    const float* x        = (const float*)d_in[0];
    const int*   ei       = (const int*)d_in[1];    // int32 per harness contract
    const float* W1       = (const float*)d_in[2];
    const float* att_src1 = (const float*)d_in[3];
    const float* att_dst1 = (const float*)d_in[4];
    const float* b1       = (const float*)d_in[5];
    const float* W2       = (const float*)d_in[6];
    const float* att_src2 = (const float*)d_in[7];
    const float* att_dst2 = (const float*)d_in[8];
    const float* b2       = (const float*)d_in[9];
    float* out = (float*)d_out;

    // workspace layout (~24 MB)
    unsigned short* h1b = (unsigned short*)d_ws;         // 20000*512 bf16
    float* as1 = (float*)(h1b + (size_t)N_NODES * 512);  // 20000*8
    float* ad1 = as1 + N_NODES * 8;                      // 20000*8
    float4* p2 = (float4*)(ad1 + N_NODES * 8);           // 20000 float4
    float* a2d = (float*)(p2 + N_NODES);                 // 20000
    int* counts  = (int*)(a2d + N_NODES);                // 20000
    int* offs    = counts + N_NODES;                     // 20001 (+pad)
    int* cursor  = offs + N_NODES + 8;                   // 20000
    int* local   = cursor + N_NODES;                     // 20000
    int* partials= local + N_NODES;                      // 80
    int* pbase   = partials + 128;                       // 80
    int* esorted = pbase + 128;                          // 340000

    hipMemsetAsync(counts, 0, N_NODES * sizeof(int), stream);

    int eb = (E_TOT + 255) / 256;
    hist_k<<<eb, 256, 0, stream>>>(ei, counts);
    scanA_k<<<NBLK, 256, 0, stream>>>(counts, local, partials);
    scanB_k<<<1, 128, 0, stream>>>(partials, pbase);
    scanC_k<<<NBLK, 256, 0, stream>>>(local, pbase, offs, cursor);
    scatter_k<<<eb, 256, 0, stream>>>(ei, cursor, esorted);

    dim3 ggrid((N_NODES + 63) / 64, 8);
    gemm1_k<<<ggrid, 256, 0, stream>>>(x, W1, att_src1, att_dst1, h1b, as1, ad1);

    agg1_k<<<N_NODES, 256, 0, stream>>>((const uint4*)h1b, as1, ad1, offs, esorted,
                                        b1, W2, att_src2, att_dst2, p2, a2d);
    int nwb = (N_NODES * 64 + 255) / 256;
    agg2_k<<<nwb, 256, 0, stream>>>(p2, a2d, offs, esorted, b2, out);
}

// Round 5
// 194.729 us; speedup vs baseline: 1.6830x; 1.1609x over previous
//
#include <hip/hip_runtime.h>
#include <math.h>

#define N_NODES 20000
#define E_EDGES 320000
#define E_TOT   (E_EDGES + N_NODES)   // 340000 (edges + self loops)
#define NEG_SLOPE 0.2f
#define NBLK 79                       // ceil(N_NODES/256)

// prep_hist_k block ranges
#define XCAST_BLKS 2500               // 20000*128/4 elems / 256
#define W1T_BLKS   256                // 512*128 elems / 256
#define HIST_BLKS  1329               // ceil(E_TOT/256)

typedef __attribute__((ext_vector_type(8))) short bf16x8;
typedef __attribute__((ext_vector_type(4))) float f32x4;

__device__ __forceinline__ float lrelu(float x) { return x > 0.f ? x : NEG_SLOPE * x; }
__device__ __forceinline__ float bflo(unsigned int v) { return __builtin_bit_cast(float, v << 16); }
__device__ __forceinline__ float bfhi(unsigned int v) { return __builtin_bit_cast(float, v & 0xffff0000u); }
__device__ __forceinline__ unsigned int f2bf(float f) {
    return (__builtin_bit_cast(unsigned int, f) + 0x8000u) >> 16;
}

// ---- fused prep: x->bf16 cast | W1^T bf16 build | degree histogram ----------
// Harness delivers ALL integer inputs as int32 — edge_index is const int*.

__global__ void prep_hist_k(const float* __restrict__ x, unsigned int* __restrict__ xb2,
                            const float* __restrict__ W1, unsigned short* __restrict__ w1t,
                            const int* __restrict__ ei, int* __restrict__ counts) {
    int b = blockIdx.x, t = threadIdx.x;
    if (b < XCAST_BLKS) {
        int idx = b * 256 + t;                   // one float4 -> uint2 (4 bf16)
        float4 v = ((const float4*)x)[idx];
        xb2[idx * 2]     = f2bf(v.x) | (f2bf(v.y) << 16);
        xb2[idx * 2 + 1] = f2bf(v.z) | (f2bf(v.w) << 16);
    } else if (b < XCAST_BLKS + W1T_BLKS) {
        int id = (b - XCAST_BLKS) * 256 + t;     // w1t[n][k] = bf16(W1[k][n])
        int n = id >> 7, k = id & 127;
        w1t[n * 128 + k] = (unsigned short)f2bf(W1[k * 512 + n]);
    } else {
        int e = (b - XCAST_BLKS - W1T_BLKS) * 256 + t;
        if (e < E_TOT) {
            int d = (e < E_EDGES) ? ei[E_EDGES + e] : (e - E_EDGES);
            atomicAdd(&counts[d], 1);
        }
    }
}

// ---------------- hierarchical scan -> scatter ----------------

__global__ void scanA_k(const int* __restrict__ counts, int* __restrict__ local,
                        int* __restrict__ partials) {
    __shared__ int sdata[256];
    int b = blockIdx.x, t = threadIdx.x;
    int idx = b * 256 + t;
    int v = (idx < N_NODES) ? counts[idx] : 0;
    sdata[t] = v;
    __syncthreads();
    for (int o = 1; o < 256; o <<= 1) {
        int u = (t >= o) ? sdata[t - o] : 0;
        __syncthreads();
        sdata[t] += u;
        __syncthreads();
    }
    if (idx < N_NODES) local[idx] = sdata[t] - v;   // exclusive within block
    if (t == 255) partials[b] = sdata[255];
}

__global__ void scanB_k(const int* __restrict__ partials, int* __restrict__ pbase) {
    __shared__ int s[128];
    int t = threadIdx.x;
    int v = (t < NBLK) ? partials[t] : 0;
    s[t] = v;
    __syncthreads();
    for (int o = 1; o < 128; o <<= 1) {
        int u = (t >= o) ? s[t - o] : 0;
        __syncthreads();
        s[t] += u;
        __syncthreads();
    }
    if (t < NBLK) pbase[t] = s[t] - v;              // exclusive
}

__global__ void scanC_k(const int* __restrict__ local, const int* __restrict__ pbase,
                        int* __restrict__ offs, int* __restrict__ cursor) {
    int idx = blockIdx.x * 256 + threadIdx.x;
    if (idx < N_NODES) {
        int o = local[idx] + pbase[blockIdx.x];
        offs[idx] = o;
        cursor[idx] = o;
    }
    if (idx == 0) offs[N_NODES] = E_TOT;
}

__global__ void scatter_k(const int* __restrict__ ei, int* __restrict__ cursor,
                          int* __restrict__ esorted) {
    int e = blockIdx.x * blockDim.x + threadIdx.x;
    if (e >= E_TOT) return;
    int s, d;
    if (e < E_EDGES) { s = ei[e]; d = ei[E_EDGES + e]; }
    else             { s = e - E_EDGES; d = s; }
    int pos = atomicAdd(&cursor[d], 1);
    esorted[pos] = s;
}

// ---- GEMM1 (bf16 MFMA) + fused att1 -----------------------------------------
// h = x@W1, 16x16x32 bf16 MFMA. Block = 64 rows x 64 cols (one head).
// LDS tiles stored [row][k] with k contiguous, +8 bf16 row pad (stride 136):
// frag loads are one ds_read_b128, conflict-free per 8-lane issue group.
// A-frag: lane holds A[m=lane&15][k=quad*8+j]; B-frag: B[k=quad*8+j][n=lane&15]
// (w1t is K-contiguous so B loads are contiguous too).
// C/D: col=lane&15, row=quad*4+reg.

__global__ __launch_bounds__(256) void gemm1_k(const unsigned short* __restrict__ xb,
                                               const unsigned short* __restrict__ w1t,
                                               const float* __restrict__ att_s,
                                               const float* __restrict__ att_d,
                                               unsigned short* __restrict__ Hb,
                                               float* __restrict__ as_,
                                               float* __restrict__ ad_) {
    __shared__ unsigned short As[64 * 136];
    __shared__ unsigned short Bs[64 * 136];
    int t = threadIdx.x;
    int m0 = blockIdx.x * 64;
    int head = blockIdx.y;
    // stage A: 64 rows x 128 bf16 (1024 uint4 chunks), guard last row block
    #pragma unroll
    for (int c = 0; c < 4; c++) {
        int idx = c * 256 + t;
        int row = idx >> 4, c16 = idx & 15;
        uint4 v = make_uint4(0u, 0u, 0u, 0u);
        int gm = m0 + row;
        if (gm < N_NODES) v = ((const uint4*)xb)[gm * 16 + c16];
        *(uint4*)&As[row * 136 + c16 * 8] = v;
    }
    // stage B: 64 n-rows x 128 bf16 from w1t[head*64 + n][k]
    #pragma unroll
    for (int c = 0; c < 4; c++) {
        int idx = c * 256 + t;
        int row = idx >> 4, c16 = idx & 15;
        uint4 v = ((const uint4*)w1t)[(head * 64 + row) * 16 + c16];
        *(uint4*)&Bs[row * 136 + c16 * 8] = v;
    }
    __syncthreads();

    int lane = t & 63, w = t >> 6;
    int r = lane & 15, q = lane >> 4;
    f32x4 acc[4] = {{0.f,0.f,0.f,0.f},{0.f,0.f,0.f,0.f},{0.f,0.f,0.f,0.f},{0.f,0.f,0.f,0.f}};
    #pragma unroll
    for (int k0 = 0; k0 < 128; k0 += 32) {
        bf16x8 af = *(const bf16x8*)&As[(w * 16 + r) * 136 + k0 + q * 8];
        #pragma unroll
        for (int nt = 0; nt < 4; nt++) {
            bf16x8 bf = *(const bf16x8*)&Bs[(nt * 16 + r) * 136 + k0 + q * 8];
            acc[nt] = __builtin_amdgcn_mfma_f32_16x16x32_bf16(af, bf, acc[nt], 0, 0, 0);
        }
    }
    // epilogue: attention dot + bf16 stores
    float sa[4], da[4];
    #pragma unroll
    for (int nt = 0; nt < 4; nt++) {
        sa[nt] = att_s[head * 64 + nt * 16 + r];
        da[nt] = att_d[head * 64 + nt * 16 + r];
    }
    #pragma unroll
    for (int i = 0; i < 4; i++) {
        int m = m0 + w * 16 + q * 4 + i;
        float ps = acc[0][i]*sa[0] + acc[1][i]*sa[1] + acc[2][i]*sa[2] + acc[3][i]*sa[3];
        float pd = acc[0][i]*da[0] + acc[1][i]*da[1] + acc[2][i]*da[2] + acc[3][i]*da[3];
        // reduce over cols (r = lane&15, within quad group)
        ps += __shfl_xor(ps, 1); ps += __shfl_xor(ps, 2);
        ps += __shfl_xor(ps, 4); ps += __shfl_xor(ps, 8);
        pd += __shfl_xor(pd, 1); pd += __shfl_xor(pd, 2);
        pd += __shfl_xor(pd, 4); pd += __shfl_xor(pd, 8);
        if (m < N_NODES) {
            if (r == 0) { as_[m * 8 + head] = ps; ad_[m * 8 + head] = pd; }
            #pragma unroll
            for (int nt = 0; nt < 4; nt++) {
                float v = acc[nt][i];
                float vn = __shfl_xor(v, 1);           // neighbor col
                if ((r & 1) == 0) {
                    unsigned int pk = f2bf(v) | (f2bf(vn) << 16);
                    *(unsigned int*)&Hb[(size_t)m * 512 + head * 64 + nt * 16 + r] = pk;
                }
            }
        }
    }
}

// ---- layer-1 softmax-aggregation: ONE WAVE PER NODE --------------------------
// Lane owns 8 contiguous feature elems (one uint4 bf16 per edge, coalesced
// 1 KB/row per wave). All edges handled by one wave, so each lane's running
// dsum IS the full denominator for its head — no reduction, no LDS at all.
// Epilogue fuses bias+ELU+512x2 layer-2 projection (wave shuffle reduce).

__global__ __launch_bounds__(256) void agg1_k(const uint4* __restrict__ hu4,
                                              const float* __restrict__ as_,
                                              const float* __restrict__ ad_,
                                              const int* __restrict__ offs,
                                              const int* __restrict__ esorted,
                                              const float* __restrict__ b1,
                                              const float* __restrict__ W2,
                                              const float* __restrict__ as2,
                                              const float* __restrict__ ad2,
                                              float4* __restrict__ p2,
                                              float* __restrict__ a2d) {
    int i = (blockIdx.x << 2) + (threadIdx.x >> 6);
    if (i >= N_NODES) return;
    int lane = threadIdx.x & 63;
    int hd = lane >> 3;
    int off = offs[i], deg = offs[i + 1] - off;
    float adh = ad_[i * 8 + hd];
    float acc[8] = {0.f, 0.f, 0.f, 0.f, 0.f, 0.f, 0.f, 0.f};
    float dsum = 0.f;
    int e = 0;
    for (; e + 2 <= deg; e += 2) {
        int s0 = esorted[off + e];
        int s1 = esorted[off + e + 1];
        float a0 = as_[s0 * 8 + hd];
        float a1 = as_[s1 * 8 + hd];
        uint4 v0 = hu4[s0 * 64 + lane];
        uint4 v1 = hu4[s1 * 64 + lane];
        float c0 = __expf(lrelu(a0 + adh));
        float c1 = __expf(lrelu(a1 + adh));
        dsum += c0 + c1;
        acc[0] += c0 * bflo(v0.x); acc[1] += c0 * bfhi(v0.x);
        acc[2] += c0 * bflo(v0.y); acc[3] += c0 * bfhi(v0.y);
        acc[4] += c0 * bflo(v0.z); acc[5] += c0 * bfhi(v0.z);
        acc[6] += c0 * bflo(v0.w); acc[7] += c0 * bfhi(v0.w);
        acc[0] += c1 * bflo(v1.x); acc[1] += c1 * bfhi(v1.x);
        acc[2] += c1 * bflo(v1.y); acc[3] += c1 * bfhi(v1.y);
        acc[4] += c1 * bflo(v1.z); acc[5] += c1 * bfhi(v1.z);
        acc[6] += c1 * bflo(v1.w); acc[7] += c1 * bfhi(v1.w);
    }
    if (e < deg) {
        int s0 = esorted[off + e];
        float a0 = as_[s0 * 8 + hd];
        uint4 v0 = hu4[s0 * 64 + lane];
        float c0 = __expf(lrelu(a0 + adh));
        dsum += c0;
        acc[0] += c0 * bflo(v0.x); acc[1] += c0 * bfhi(v0.x);
        acc[2] += c0 * bflo(v0.y); acc[3] += c0 * bfhi(v0.y);
        acc[4] += c0 * bflo(v0.z); acc[5] += c0 * bfhi(v0.z);
        acc[6] += c0 * bflo(v0.w); acc[7] += c0 * bfhi(v0.w);
    }
    float inv = 1.f / dsum;          // dsum identical across the head's 8 lanes
    float4 bA = *(const float4*)&b1[lane * 8];
    float4 bB = *(const float4*)&b1[lane * 8 + 4];
    float bb[8] = {bA.x, bA.y, bA.z, bA.w, bB.x, bB.y, bB.z, bB.w};
    float p0 = 0.f, p1 = 0.f;
    #pragma unroll
    for (int j = 0; j < 8; j++) {
        float v = acc[j] * inv + bb[j];
        v = v > 0.f ? v : expm1f(v);
        int col = lane * 8 + j;
        p0 += v * W2[col * 2];
        p1 += v * W2[col * 2 + 1];
    }
    #pragma unroll
    for (int m = 1; m < 64; m <<= 1) { p0 += __shfl_xor(p0, m); p1 += __shfl_xor(p1, m); }
    if (lane == 0) {
        float a2sv = p0 * as2[0] + p1 * as2[1];
        p2[i] = make_float4(p0, p1, a2sv, 0.f);
        a2d[i] = p0 * ad2[0] + p1 * ad2[1];
    }
}

// ---- layer-2 single-pass softmax + aggregation, wave per dst node ----
// p2[s] = (h2c0, h2c1, a2s, -) : one dwordx4 gather per edge.

__global__ void agg2_k(const float4* __restrict__ p2, const float* __restrict__ a2d,
                       const int* __restrict__ offs, const int* __restrict__ esorted,
                       const float* __restrict__ b2, float* __restrict__ out) {
    int gid = blockIdx.x * blockDim.x + threadIdx.x;
    int wid = gid >> 6;
    int lane = threadIdx.x & 63;
    if (wid >= N_NODES) return;
    int off = offs[wid], deg = offs[wid + 1] - off;
    float adi = a2d[wid];
    float lsum = 0.f, o0 = 0.f, o1 = 0.f;
    for (int e = lane; e < deg; e += 64) {
        int s = esorted[off + e];
        float4 q = p2[s];
        float ex = __expf(lrelu(q.z + adi));
        lsum += ex;
        o0 += ex * q.x;
        o1 += ex * q.y;
    }
    #pragma unroll
    for (int m = 1; m < 64; m <<= 1) {
        lsum += __shfl_xor(lsum, m);
        o0 += __shfl_xor(o0, m);
        o1 += __shfl_xor(o1, m);
    }
    if (lane == 0) {
        float inv = 1.f / lsum;
        out[wid * 2]     = o0 * inv + b2[0];
        out[wid * 2 + 1] = o1 * inv + b2[1];
    }
}

// ---------------- launch ----------------

extern "C" void kernel_launch(void* const* d_in, const int* in_sizes, int n_in,
                              void* d_out, int out_size, void* d_ws, size_t ws_size,
                              hipStream_t stream) {
    const float* x        = (const float*)d_in[0];
    const int*   ei       = (const int*)d_in[1];    // int32 per harness contract
    const float* W1       = (const float*)d_in[2];
    const float* att_src1 = (const float*)d_in[3];
    const float* att_dst1 = (const float*)d_in[4];
    const float* b1       = (const float*)d_in[5];
    const float* W2       = (const float*)d_in[6];
    const float* att_src2 = (const float*)d_in[7];
    const float* att_dst2 = (const float*)d_in[8];
    const float* b2       = (const float*)d_in[9];
    float* out = (float*)d_out;

    // workspace layout (~31 MB)
    unsigned short* h1b = (unsigned short*)d_ws;         // 20000*512 bf16
    unsigned short* xb  = h1b + (size_t)N_NODES * 512;   // 20000*128 bf16
    unsigned short* w1t = xb + (size_t)N_NODES * 128;    // 512*128 bf16
    float* as1 = (float*)(w1t + 512 * 128);              // 20000*8
    float* ad1 = as1 + N_NODES * 8;                      // 20000*8
    float4* p2 = (float4*)(ad1 + N_NODES * 8);           // 20000 float4
    float* a2d = (float*)(p2 + N_NODES);                 // 20000
    int* counts  = (int*)(a2d + N_NODES);                // 20000
    int* offs    = counts + N_NODES;                     // 20001 (+pad)
    int* cursor  = offs + N_NODES + 8;                   // 20000
    int* local   = cursor + N_NODES;                     // 20000
    int* partials= local + N_NODES;                      // 80
    int* pbase   = partials + 128;                       // 80
    int* esorted = pbase + 128;                          // 340000

    hipMemsetAsync(counts, 0, N_NODES * sizeof(int), stream);

    prep_hist_k<<<XCAST_BLKS + W1T_BLKS + HIST_BLKS, 256, 0, stream>>>(
        x, (unsigned int*)xb, W1, w1t, ei, counts);
    scanA_k<<<NBLK, 256, 0, stream>>>(counts, local, partials);
    scanB_k<<<1, 128, 0, stream>>>(partials, pbase);
    scanC_k<<<NBLK, 256, 0, stream>>>(local, pbase, offs, cursor);
    int eb = (E_TOT + 255) / 256;
    scatter_k<<<eb, 256, 0, stream>>>(ei, cursor, esorted);

    dim3 ggrid((N_NODES + 63) / 64, 8);
    gemm1_k<<<ggrid, 256, 0, stream>>>(xb, w1t, att_src1, att_dst1, h1b, as1, ad1);

    agg1_k<<<(N_NODES + 3) / 4, 256, 0, stream>>>((const uint4*)h1b, as1, ad1, offs,
                                                  esorted, b1, W2, att_src2, att_dst2,
                                                  p2, a2d);
    int nwb = (N_NODES * 64 + 255) / 256;
    agg2_k<<<nwb, 256, 0, stream>>>(p2, a2d, offs, esorted, b2, out);
}